// Round 9
// baseline (250.820 us; speedup 1.0000x reference)
//
#include <hip/hip_runtime.h>

// B=64, S=512, D=256, VOCAB=50000, NC=10, N_STEPS=10 (h=0.1), BN eval.
// z_final = z0 @ P10 + c10, P10 = M^10, M = Taylor4(exp(hA)), A = W^T.
// Transpose trick: M = N^T, N = I + B, B = 0.1W + 0.005W^2 + (1e-3/6)W^3 + (1e-4/24)W^4,
// so P10 = (N^10)^T; the transpose is absorbed into the slab fragment scatter.
//
// LESSONS (R1-R8):
//  - Intra-kernel global sync: 70-110us/event on MI355X (all styles). Rejected.
//  - Prep passes are LOAD-LATENCY bound, not BW/VALU: R8 prep3 = 53us with
//    VALUBusy 4.7% = 16 serial load-window exposures x ~2000cyc cross-XCD
//    dirty-line migration (plain-stored N2 dirty in 8 L2s; 23.8MB forced
//    writebacks visible in WRITE_SIZE).
//  - THIS ROUND: (a) ONE 64-deep load window per pass (bv[64] in VGPRs);
//    (b) agent-scope stores (bypass L2, clean lines at coherence point) for
//    all cross-dispatch buffers - consumers pay clean L3 fills, not probes.
//    Write path correctness proven in R7. k_main/k_fin unchanged (proven).

typedef short bf16x8 __attribute__((ext_vector_type(8)));
typedef float f32x4 __attribute__((ext_vector_type(4)));

__device__ __forceinline__ unsigned short f2bf(float f) {
  unsigned u = __float_as_uint(f);
  u += 0x7FFFu + ((u >> 16) & 1u);   // RNE; inputs are normal floats
  return (unsigned short)(u >> 16);
}

// agent-scope (bypass-L2) stores: land clean at the coherence point
__device__ __forceinline__ void gstf(float* p, float v) {
  __hip_atomic_store(p, v, __ATOMIC_RELAXED, __HIP_MEMORY_SCOPE_AGENT);
}
__device__ __forceinline__ void gst16(unsigned short* p, unsigned short v) {
  __hip_atomic_store(p, v, __ATOMIC_RELAXED, __HIP_MEMORY_SCOPE_AGENT);
}
__device__ __forceinline__ void gstu(unsigned* p, unsigned v) {
  __hip_atomic_store(p, v, __ATOMIC_RELAXED, __HIP_MEMORY_SCOPE_AGENT);
}

// One row-GEMM pass, 1024 threads: dst_row = src_row @ Y.
// Thread t: col c = t&255, K-group g = t>>8 (64 rows of Y).
// ALL 64 loads issued in ONE window (bv[64] in VGPRs) -> single latency hit.
__device__ __forceinline__ void rstep64(float* __restrict__ dst, const float* __restrict__ src,
                                        const float* __restrict__ Y, float* __restrict__ part,
                                        int t) {
  const int c = t & 255, g = t >> 8;
  const float* Yc = Y + (size_t)(g * 64) * 256 + c;
  const float* sg = src + g * 64;
  float bv[64];
#pragma unroll
  for (int v = 0; v < 64; ++v) bv[v] = Yc[v * 256];
  float a0 = 0.f, a1 = 0.f, a2 = 0.f, a3 = 0.f;
#pragma unroll
  for (int v = 0; v < 64; v += 4) {
    a0 = fmaf(sg[v + 0], bv[v + 0], a0);
    a1 = fmaf(sg[v + 1], bv[v + 1], a1);
    a2 = fmaf(sg[v + 2], bv[v + 2], a2);
    a3 = fmaf(sg[v + 3], bv[v + 3], a3);
  }
  part[t] = (a0 + a1) + (a2 + a3);
  __syncthreads();
  if (t < 256) dst[t] = (part[t] + part[t + 256]) + (part[t + 512] + part[t + 768]);
  __syncthreads();
}

// ---- d1: blocks 0-255: row chain W->W2->W3->W4 -> B row + c1[i] (agent stores).
//          blocks 256-351: conv repack (4 elems/thread) + featbuf zero.
__global__ __launch_bounds__(1024) void k_prep1(
    const float* __restrict__ W, const float* __restrict__ bode,
    const float* __restrict__ w3c, const float* __restrict__ w4c, const float* __restrict__ w5c,
    float* __restrict__ Bm, float* __restrict__ c1,
    unsigned short* __restrict__ slab, unsigned* __restrict__ featbuf) {
  __shared__ float part[1024], ra[256], rb[256], rc[256], rd[256], red[4];
  const int t = threadIdx.x, blk = blockIdx.x;
  if (blk < 256) {
    const int i = blk;
    if (t < 256) ra[t] = W[i * 256 + t];
    __syncthreads();
    rstep64(rb, ra, W, part, t);   // W2 row
    rstep64(rc, rb, W, part, t);   // W3 row
    rstep64(rd, rc, W, part, t);   // W4 row
    if (t < 256) {
      gstf(&Bm[i * 256 + t], 0.1f * ra[t] + 0.005f * rb[t]
                           + (0.001f / 6.f) * rc[t] + (0.0001f / 24.f) * rd[t]);
      const float q = 0.05f * ra[t] + (0.01f / 6.f) * rb[t] + (0.001f / 24.f) * rc[t];
      float val = bode[t] * q;
#pragma unroll
      for (int off = 32; off > 0; off >>= 1) val += __shfl_down(val, off);
      if ((t & 63) == 0) red[t >> 6] = val;
    }
    __syncthreads();
    if (t == 0) gstf(&c1[i], 0.1f * (bode[i] + ((red[0] + red[1]) + (red[2] + red[3]))));
  } else {
    const int base = (blk - 256) * 1024 + t;    // 0..98303
#pragma unroll
    for (int u = 0; u < 4; ++u) {
      int e = base + u * 98304;                 // covers 0..393215 = 12*32768
      int s = e >> 15, r = e & 32767, kd = r >> 7, o = r & 127;
      const float* w; int k, j;
      if (s < 3)      { w = w3c; k = 3; j = s; }
      else if (s < 7) { w = w4c; k = 4; j = s - 3; }
      else            { w = w5c; k = 5; j = s - 7; }
      float val = w[(o * 256 + kd) * k + j];    // w[o][d=kd][j], shape (128,256,k)
      int kc = kd >> 5, quad = (kd >> 3) & 3, q8 = kd & 7;
      gst16(&slab[s * 32768 + ((kc * 4 + quad) * 128 + o) * 8 + q8], f2bf(val));
    }
    if (base < 64 * 640) gstu(&featbuf[base], 0u);
  }
}

// ---- d2: N2 = I + 2B + B^2 (one pass, Y=B)
__global__ __launch_bounds__(1024) void k_prep2(const float* __restrict__ Bm,
                                                float* __restrict__ N2) {
  __shared__ float part[1024], ra[256], rb[256];
  const int t = threadIdx.x, i = blockIdx.x;
  if (t < 256) ra[t] = Bm[i * 256 + t];
  __syncthreads();
  rstep64(rb, ra, Bm, part, t);
  if (t < 256) gstf(&N2[i * 256 + t], ((i == t) ? 1.f : 0.f) + 2.f * ra[t] + rb[t]);
}

// ---- d3: blocks 0-255: row chain N2[i] x (N2)^4 = N10[i] -> slab node scatter.
//          block 256: c-chain, one 64-load window per step.
__global__ __launch_bounds__(1024) void k_prep3(
    const float* __restrict__ Bm, const float* __restrict__ N2,
    const float* __restrict__ c1, float* __restrict__ c10,
    unsigned short* __restrict__ slab) {
  __shared__ float part[1024], ra[256], rb[256], rc[256], rd[256];
  const int t = threadIdx.x, blk = blockIdx.x;
  if (blk < 256) {
    if (t < 256) ra[t] = N2[blk * 256 + t];
    __syncthreads();
    rstep64(ra, ra, N2, part, t);
    rstep64(ra, ra, N2, part, t);
    rstep64(ra, ra, N2, part, t);
    rstep64(ra, ra, N2, part, t);
    if (t < 256) {
      // ra[t] = N10[o=blk][kd=t] = P10[kd][o]
      const int o = blk, kd = t;
      const int kc = kd >> 5, quad = (kd >> 3) & 3, q8 = kd & 7;
      gst16(&slab[(12 + (o >> 7)) * 32768 + ((kc * 4 + quad) * 128 + (o & 127)) * 8 + q8],
            f2bf(ra[t]));
    }
  } else {
    // c-chain: 16 waves x 16 rows; ALL 64 loads of a step in ONE window.
    const int w = t >> 6, lane = t & 63;
    if (t < 256) { ra[t] = c1[t]; rd[t] = 2.f * c1[t]; }
    __syncthreads();
    // DST[j] = ADD2[j] + sum_k SRC[k]*YMAT[j][k]
#define CSTEP(SRC, YMAT, ADD2, DST)                                             \
    {                                                                           \
      float bv[16][4];                                                          \
      _Pragma("unroll")                                                         \
      for (int rr = 0; rr < 16; ++rr) {                                         \
        const int j = w * 16 + rr;                                              \
        _Pragma("unroll")                                                       \
        for (int q = 0; q < 4; ++q) bv[rr][q] = YMAT[j * 256 + lane + 64 * q];  \
      }                                                                         \
      _Pragma("unroll")                                                         \
      for (int rr = 0; rr < 16; ++rr) {                                         \
        const int j = w * 16 + rr;                                              \
        float v = 0.f;                                                          \
        _Pragma("unroll")                                                       \
        for (int q = 0; q < 4; ++q) v = fmaf(SRC[lane + 64 * q], bv[rr][q], v); \
        _Pragma("unroll")                                                       \
        for (int off = 32; off > 0; off >>= 1) v += __shfl_down(v, off);        \
        if (lane == 0) DST[j] = ADD2[j] + v;                                    \
      }                                                                         \
      __syncthreads();                                                          \
    }
    CSTEP(ra, Bm, rd, rb)   // rb = c2 = 2c1 + c1.B-rows
    CSTEP(rb, N2, rb, rc)   // rc = c4
    CSTEP(rc, N2, rb, rd)   // rd = c6
    CSTEP(rd, N2, rb, rc)   // rc = c8
    CSTEP(rc, N2, rb, rd)   // rd = c10
#undef CSTEP
    if (t < 256) gstf(&c10[t], rd[t]);
  }
}

// ---------------- fused main kernel (R5 structure + depth-4 pipeline, proven) ----------------
// grid 512 = 64 batches x 8 t-chunks of 64. 256 threads = 4 waves.
// LDS: only the X tile. B-fragments read per-wave directly from the
// L2/L3-resident slab with a 4-deep register pipeline; no barriers in main loop.

__global__ __launch_bounds__(256, 2) void k_main(
    const int* __restrict__ ids, const float* __restrict__ emb,
    const unsigned short* __restrict__ slab, const float* __restrict__ ctot,
    const float* __restrict__ b3, const float* __restrict__ g3, const float* __restrict__ be3,
    const float* __restrict__ b4, const float* __restrict__ g4, const float* __restrict__ be4,
    const float* __restrict__ b5, const float* __restrict__ g5, const float* __restrict__ be5,
    unsigned* __restrict__ featbuf) {
  __shared__ alignas(16) unsigned short Xt[68 * 264];
  __shared__ int ids_s[68];
  const int tid = threadIdx.x;
  const int blk = blockIdx.x;
  const int b = blk >> 3;
  const int t0 = (blk & 7) * 64;
  const int lane = tid & 63;
  const int wave = tid >> 6;
  const int m15 = lane & 15;
  const int quad = lane >> 4;

  if (tid < 68) {
    int t = t0 + tid;
    ids_s[tid] = (t < 512) ? ids[b * 512 + t] : -1;
  }
  __syncthreads();

  // per-lane B-fragment base; frag(e,kc2,nt) = fb0 + e*8192 + kc2*4096 + nt*128
  const unsigned short* fb0 = slab + ((size_t)quad * 128 + wave * 2 * 16 + m15) * 8;
  bf16x8 fA[4], fB[4], fC[4], fD[4];   // [kc2*2+nt], 4-deep entry pipeline
#define LDFRAG(DST, EN)                                                         \
  {                                                                             \
    const unsigned short* p_ = fb0 + (EN) * 8192;                               \
    DST[0] = *(const bf16x8*)(p_);                                              \
    DST[1] = *(const bf16x8*)(p_ + 128);                                        \
    DST[2] = *(const bf16x8*)(p_ + 4096);                                       \
    DST[3] = *(const bf16x8*)(p_ + 4096 + 128);                                 \
  }
  LDFRAG(fA, 0) LDFRAG(fB, 1) LDFRAG(fC, 2) LDFRAG(fD, 3)

  // gather + fp32->bf16 X tile (overlaps the frag loads above)
  for (int i = tid; i < 68 * 64; i += 256) {
    int row = i >> 6, s4 = i & 63;
    uint2 v = make_uint2(0u, 0u);
    int id = ids_s[row];
    if (id >= 0) {
      const float4 f = *(const float4*)(emb + (size_t)id * 256 + s4 * 4);
      v.x = (unsigned)f2bf(f.x) | ((unsigned)f2bf(f.y) << 16);
      v.y = (unsigned)f2bf(f.z) | ((unsigned)f2bf(f.w) << 16);
    }
    *(uint2*)&Xt[row * 264 + s4 * 4] = v;
  }
  __syncthreads();  // Xt ready; no further barriers

  f32x4 acc[4][2];
#pragma unroll
  for (int mt = 0; mt < 4; ++mt)
#pragma unroll
    for (int nt = 0; nt < 2; ++nt) acc[mt][nt] = (f32x4){0.f, 0.f, 0.f, 0.f};

#define ENTRY(KCQ, FR)                                                          \
  {                                                                             \
    _Pragma("unroll")                                                           \
    for (int kc2 = 0; kc2 < 2; ++kc2) {                                         \
      const int kd0 = ((KCQ) * 2 + kc2) * 32 + quad * 8;                        \
      bf16x8 af[4];                                                             \
      _Pragma("unroll")                                                         \
      for (int mt = 0; mt < 4; ++mt)                                            \
        af[mt] = *(const bf16x8*)&Xt[(shift + mt * 16 + m15) * 264 + kd0];      \
      _Pragma("unroll")                                                         \
      for (int mt = 0; mt < 4; ++mt) {                                          \
        acc[mt][0] = __builtin_amdgcn_mfma_f32_16x16x32_bf16(af[mt], FR[kc2 * 2 + 0], acc[mt][0], 0, 0, 0); \
        acc[mt][1] = __builtin_amdgcn_mfma_f32_16x16x32_bf16(af[mt], FR[kc2 * 2 + 1], acc[mt][1], 0, 0, 0); \
      }                                                                         \
    }                                                                           \
  }

  // entries e = eq*4 + j; slice = eq; kcq = j; epilogues at eq 2,6,11,12,13.
  for (int eq = 0; eq < 14; ++eq) {
    const int shift = (eq < 3) ? eq : (eq < 7) ? (eq - 3) : (eq < 12) ? (eq - 7) : 0;

    ENTRY(0, fA) if (eq < 13) LDFRAG(fA, (eq + 1) * 4 + 0)
    ENTRY(1, fB) if (eq < 13) LDFRAG(fB, (eq + 1) * 4 + 1)
    ENTRY(2, fC) if (eq < 13) LDFRAG(fC, (eq + 1) * 4 + 2)
    ENTRY(3, fD) if (eq < 13) LDFRAG(fD, (eq + 1) * 4 + 3)

    const int g = (eq == 2) ? 0 : (eq == 6) ? 1 : (eq == 11) ? 2
                : (eq == 12) ? 3 : (eq == 13) ? 4 : -1;
    if (g >= 0) {
      if (g < 3) {
        const int kk = g + 3;
        const float* bb  = (g == 0) ? b3 : (g == 1) ? b4 : b5;
        const float* gg  = (g == 0) ? g3 : (g == 1) ? g4 : g5;
        const float* bbe = (g == 0) ? be3 : (g == 1) ? be4 : be5;
        const int off = 256 + g * 128;     // feats: [node 256][p3 128][p4 128][p5 128]
        const int tmax = 512 - kk;
#pragma unroll
        for (int nt = 0; nt < 2; ++nt) {
          const int n = (wave * 2 + nt) * 16 + m15;
          const float sc = gg[n] * 0.9999950000375f;  // g * 1/sqrt(1+1e-5)
          const float sh = fmaf(sc, bb[n], bbe[n]);
          float mx = 0.f;  // relu floor doubles as init
#pragma unroll
          for (int mt = 0; mt < 4; ++mt)
#pragma unroll
            for (int r = 0; r < 4; ++r) {
              const int t = t0 + mt * 16 + quad * 4 + r;
              const float v = fmaf(sc, acc[mt][nt][r], sh);
              if (t <= tmax) mx = fmaxf(mx, v);
            }
          mx = fmaxf(mx, __shfl_xor(mx, 16));
          mx = fmaxf(mx, __shfl_xor(mx, 32));
          if (quad == 0) atomicMax(&featbuf[b * 640 + off + n], __float_as_uint(mx));
        }
      } else {
        const int base = (g == 3) ? 0 : 128;
#pragma unroll
        for (int nt = 0; nt < 2; ++nt) {
          const int n = (wave * 2 + nt) * 16 + m15;
          const float ct = ctot[base + n];
          float mx = -3.4e38f;
#pragma unroll
          for (int mt = 0; mt < 4; ++mt)
#pragma unroll
            for (int r = 0; r < 4; ++r)
              mx = fmaxf(mx, acc[mt][nt][r] + ct);
          mx = fmaxf(mx, __shfl_xor(mx, 16));
          mx = fmaxf(mx, __shfl_xor(mx, 32));
          if (quad == 0) {
            unsigned bits = __float_as_uint(mx);
            unsigned key = (bits & 0x80000000u) ? ~bits : (bits | 0x80000000u);  // order-preserving
            atomicMax(&featbuf[b * 640 + base + n], key);
          }
        }
      }
#pragma unroll
      for (int mt = 0; mt < 4; ++mt)
#pragma unroll
        for (int nt = 0; nt < 2; ++nt) acc[mt][nt] = (f32x4){0.f, 0.f, 0.f, 0.f};
    }
  }
#undef ENTRY
#undef LDFRAG
}

// ---------------- classifier ----------------
__global__ void k_fin(const unsigned* __restrict__ featbuf, const float* __restrict__ wc,
                      const float* __restrict__ bc, float* __restrict__ out) {
  int b = blockIdx.x, lane = threadIdx.x;  // 64 threads = 1 wave
  float p[10];
#pragma unroll
  for (int c = 0; c < 10; ++c) p[c] = 0.f;
  for (int f = lane; f < 640; f += 64) {
    unsigned u = featbuf[b * 640 + f];
    float v;
    if (f < 256) v = (u & 0x80000000u) ? __uint_as_float(u ^ 0x80000000u) : __uint_as_float(~u);
    else v = __uint_as_float(u);
#pragma unroll
    for (int c = 0; c < 10; ++c) p[c] = fmaf(v, wc[c * 640 + f], p[c]);
  }
#pragma unroll
  for (int c = 0; c < 10; ++c) {
    float s = p[c];
#pragma unroll
    for (int off = 32; off > 0; off >>= 1) s += __shfl_down(s, off);
    if (lane == 0) out[b * 10 + c] = s + bc[c];
  }
}

// ---------------- launcher ----------------
extern "C" void kernel_launch(void* const* d_in, const int* in_sizes, int n_in,
                              void* d_out, int out_size, void* d_ws, size_t ws_size,
                              hipStream_t stream) {
  (void)in_sizes; (void)n_in; (void)out_size; (void)ws_size;
  const int*   ids  = (const int*)d_in[0];
  const float* emb  = (const float*)d_in[1];
  const float* W    = (const float*)d_in[2];
  const float* bode = (const float*)d_in[3];
  const float* w3   = (const float*)d_in[4];
  const float* b3   = (const float*)d_in[5];
  const float* g3   = (const float*)d_in[6];
  const float* be3  = (const float*)d_in[7];
  const float* w4   = (const float*)d_in[8];
  const float* b4   = (const float*)d_in[9];
  const float* g4   = (const float*)d_in[10];
  const float* be4  = (const float*)d_in[11];
  const float* w5   = (const float*)d_in[12];
  const float* b5   = (const float*)d_in[13];
  const float* g5   = (const float*)d_in[14];
  const float* be5  = (const float*)d_in[15];
  const float* wc   = (const float*)d_in[16];
  const float* bc   = (const float*)d_in[17];
  float* out = (float*)d_out;

  float* wsf = (float*)d_ws;
  // ws layout (floats): B 0 | N2 65536 | c1 131072 | c10 131328 |
  // slab 131584 (14*32768 bf16 = 229376 floats) | featbuf 360960 (40960 uints)
  float* Bm  = wsf;
  float* N2  = wsf + 65536;
  float* c1  = wsf + 131072;
  float* c10 = wsf + 131328;
  unsigned short* slab = (unsigned short*)(wsf + 131584);
  unsigned* featbuf = (unsigned*)(wsf + 360960);

  hipLaunchKernelGGL(k_prep1, dim3(352), dim3(1024), 0, stream,
                     W, bode, w3, w4, w5, Bm, c1, slab, featbuf);
  hipLaunchKernelGGL(k_prep2, dim3(256), dim3(1024), 0, stream, Bm, N2);
  hipLaunchKernelGGL(k_prep3, dim3(257), dim3(1024), 0, stream, Bm, N2, c1, c10, slab);
  hipLaunchKernelGGL(k_main, dim3(512), dim3(256), 0, stream,
                     ids, emb, slab, c10,
                     b3, g3, be3, b4, g4, be4, b5, g5, be5, featbuf);
  hipLaunchKernelGGL(k_fin, dim3(64), dim3(64), 0, stream, featbuf, wc, bc, out);
}

// Round 10
// 200.073 us; speedup vs baseline: 1.2536x; 1.2536x over previous
//
#include <hip/hip_runtime.h>

// B=64, S=512, D=256, VOCAB=50000, NC=10, N_STEPS=10 (h=0.1), BN eval.
// z_final = z0 @ P10 + c10, P10 = M^10, M = Taylor4(exp(hA)), A = W^T.
// Transpose trick: M = N^T, N = I + B, B = 0.1W + 0.005W^2 + (1e-3/6)W^3 + (1e-4/24)W^4,
// so P10 = (N^10)^T; the transpose is absorbed into the slab fragment scatter.
// Binomial trick: N^10 = sum_k C(10,k) B^k and ctot = sum_j C(10,j+1) c1.(B^j)^T,
// so row i of EVERYTHING comes from chaining row i of B^k against the fixed,
// read-only matrix B -- 256 independent blocks, no serial c-chain, no N2.
//
// LESSONS (R1-R9):
//  - Intra-kernel global sync: 70-110us/event (all styles). Multi-dispatch it is.
//  - 1024-thread prep blocks cap VGPR at 64 -> every "deep window" spilled to
//    scratch (R8/R9: 23-26MB WRITE_SIZE vs 130KB legitimate). Use 256-thread
//    blocks (cap 256) with bv[64] windows that actually stay in registers.
//  - k_main/k_fin: R5 bodies verbatim (47.5 + 5 us, proven).

typedef short bf16x8 __attribute__((ext_vector_type(8)));
typedef float f32x4 __attribute__((ext_vector_type(4)));

__device__ __forceinline__ unsigned short f2bf(float f) {
  unsigned u = __float_as_uint(f);
  u += 0x7FFFu + ((u >> 16) & 1u);   // RNE; inputs are normal floats
  return (unsigned short)(u >> 16);
}

// acc = sum_k xrow[k] * Y[k][c]; xrow in LDS, Y global row-major, coalesced
// across c. Windows of 64 loads fully in VGPRs (needs 256-thread blocks so the
// VGPR cap is 256 -- at 1024 threads the cap is 64 and this spills!).
__device__ __forceinline__ float dotcol64(const float* __restrict__ xrow,
                                          const float* __restrict__ Y, int c) {
  float a0 = 0.f, a1 = 0.f, a2 = 0.f, a3 = 0.f;
#pragma unroll 1
  for (int w = 0; w < 4; ++w) {
    float bv[64];
#pragma unroll
    for (int v = 0; v < 64; ++v) bv[v] = Y[(w * 64 + v) * 256 + c];
#pragma unroll
    for (int v = 0; v < 64; v += 4) {
      a0 = fmaf(xrow[w * 64 + v + 0], bv[v + 0], a0);
      a1 = fmaf(xrow[w * 64 + v + 1], bv[v + 1], a1);
      a2 = fmaf(xrow[w * 64 + v + 2], bv[v + 2], a2);
      a3 = fmaf(xrow[w * 64 + v + 3], bv[v + 3], a3);
    }
  }
  return (a0 + a1) + (a2 + a3);
}

// ---- d1: blocks 0-255: W-power row chain -> B row + c1[i].
//          blocks 256-639: conv repack (4 elems/thread) + featbuf zero.
__global__ __launch_bounds__(256) void k_prep1(
    const float* __restrict__ W, const float* __restrict__ bode,
    const float* __restrict__ w3c, const float* __restrict__ w4c, const float* __restrict__ w5c,
    float* __restrict__ Bm, float* __restrict__ c1,
    unsigned short* __restrict__ slab, unsigned* __restrict__ featbuf) {
  __shared__ float r1[256], r2[256], r3[256], red[4];
  const int tid = threadIdx.x, blk = blockIdx.x;
  if (blk < 256) {
    const int i = blk;
    r1[tid] = W[i * 256 + tid];
    __syncthreads();
    const float v2 = dotcol64(r1, W, tid);   // W^2[i][tid]
    r2[tid] = v2;
    __syncthreads();
    const float v3 = dotcol64(r2, W, tid);   // W^3[i][tid]
    r3[tid] = v3;
    __syncthreads();
    const float v4 = dotcol64(r3, W, tid);   // W^4[i][tid]
    const float w1 = r1[tid];
    Bm[i * 256 + tid] = 0.1f * w1 + 0.005f * v2
                      + (0.001f / 6.f) * v3 + (0.0001f / 24.f) * v4;
    // c1[i] = 0.1*(b[i] + sum_k b[k]*(0.05 W[i,k] + (0.01/6) W2[i,k] + (0.001/24) W3[i,k]))
    const float q = 0.05f * w1 + (0.01f / 6.f) * v2 + (0.001f / 24.f) * v3;
    float val = bode[tid] * q;
#pragma unroll
    for (int off = 32; off > 0; off >>= 1) val += __shfl_down(val, off);
    if ((tid & 63) == 0) red[tid >> 6] = val;
    __syncthreads();
    if (tid == 0) c1[i] = 0.1f * (bode[i] + ((red[0] + red[1]) + (red[2] + red[3])));
  } else {
    const int base = (blk - 256) * 256 + tid;   // 0..98303
#pragma unroll
    for (int u = 0; u < 4; ++u) {
      int e = base + u * 98304;                 // covers 0..393215 = 12*32768
      int s = e >> 15, r = e & 32767, kd = r >> 7, o = r & 127;
      const float* w; int k, j;
      if (s < 3)      { w = w3c; k = 3; j = s; }
      else if (s < 7) { w = w4c; k = 4; j = s - 3; }
      else            { w = w5c; k = 5; j = s - 7; }
      float val = w[(o * 256 + kd) * k + j];    // w[o][d=kd][j], shape (128,256,k)
      int kc = kd >> 5, quad = (kd >> 3) & 3, q8 = kd & 7;
      slab[s * 32768 + ((kc * 4 + quad) * 128 + o) * 8 + q8] = f2bf(val);
    }
    if (base < 64 * 640) featbuf[base] = 0u;
  }
}

// ---- d2: block i: chain B[i] -> B^2[i] -> ... -> B^10[i] (Y=B, read-only).
// n10[i][c] = sum_k C(10,k) B^k[i][c]   (k=0..10, exact)
// ct[i]     = sum_j C(10,j+1) dot(B^j[i], c1)   (j=0..9, exact)
// Scatter n10 row to slab node slices (N10[i][d] = P10[d][i]); c10[i] = ct.
__global__ __launch_bounds__(256) void k_prep2(
    const float* __restrict__ Bm, const float* __restrict__ c1v,
    float* __restrict__ c10, unsigned short* __restrict__ slab) {
  __shared__ float curs[256], c1s[256], red[4];
  const int tid = threadIdx.x, i = blockIdx.x;
  // binomial coefficients C(10,k)
  const float coefN[11] = {1.f, 10.f, 45.f, 120.f, 210.f, 252.f,
                           210.f, 120.f, 45.f, 10.f, 1.f};
  float v = Bm[i * 256 + tid];          // B^1 row value at col tid
  curs[tid] = v;
  c1s[tid] = c1v[tid];
  float n10 = ((i == tid) ? 1.f : 0.f) + 10.f * v;   // k=0,1 terms
  // ct: j=0 term 10*c1[i]; j=1 term 45*dot(B[i],c1)
  float pd = v * c1s[tid];
#pragma unroll
  for (int off = 32; off > 0; off >>= 1) pd += __shfl_down(pd, off);
  if ((tid & 63) == 0) red[tid >> 6] = pd;
  __syncthreads();
  float ct = 10.f * c1s[i] + 45.f * ((red[0] + red[1]) + (red[2] + red[3]));

#pragma unroll 1
  for (int k = 2; k <= 10; ++k) {
    v = dotcol64(curs, Bm, tid);        // B^k[i][tid]
    n10 = fmaf(coefN[k], v, n10);
    // ct term j=k uses coefficient C(10,k+1) = coefN[k+1] * adjust:
    // C(10,j+1) for j=k -> only while k<=9
    float pdk = v * c1s[tid];
#pragma unroll
    for (int off = 32; off > 0; off >>= 1) pdk += __shfl_down(pdk, off);
    if ((tid & 63) == 0) red[tid >> 6] = pdk;
    __syncthreads();                    // red ready; all reads of curs done
    if (k <= 9) {
      // C(10,k+1): from coefN table (C(10,m) at m=k+1)
      ct = fmaf(coefN[k + 1], (red[0] + red[1]) + (red[2] + red[3]), ct);
    }
    curs[tid] = v;
    __syncthreads();
  }

  // scatter n10: element (kd=tid, o=i) of the node B-matrix
  {
    const int o = i, kd = tid;
    const int kc = kd >> 5, quad = (kd >> 3) & 3, q8 = kd & 7;
    slab[(12 + (o >> 7)) * 32768 + ((kc * 4 + quad) * 128 + (o & 127)) * 8 + q8] = f2bf(n10);
  }
  if (tid == 0) c10[i] = ct;
}

// ---------------- fused main kernel (R5 verbatim, proven 47.5us) ----------------
// grid 512 = 64 batches x 8 t-chunks of 64. 256 threads = 4 waves.
// LDS: only the X tile. B-fragments read per-wave directly from the slab
// (L2-resident, already in MFMA B-frag order) with a depth-2 register pipeline.

__global__ __launch_bounds__(256, 2) void k_main(
    const int* __restrict__ ids, const float* __restrict__ emb,
    const unsigned short* __restrict__ slab, const float* __restrict__ ctot,
    const float* __restrict__ b3, const float* __restrict__ g3, const float* __restrict__ be3,
    const float* __restrict__ b4, const float* __restrict__ g4, const float* __restrict__ be4,
    const float* __restrict__ b5, const float* __restrict__ g5, const float* __restrict__ be5,
    unsigned* __restrict__ featbuf) {
  __shared__ alignas(16) unsigned short Xt[68 * 264];
  __shared__ int ids_s[68];
  const int tid = threadIdx.x;
  const int blk = blockIdx.x;
  const int b = blk >> 3;
  const int t0 = (blk & 7) * 64;
  const int lane = tid & 63;
  const int wave = tid >> 6;
  const int m15 = lane & 15;
  const int quad = lane >> 4;

  if (tid < 68) {
    int t = t0 + tid;
    ids_s[tid] = (t < 512) ? ids[b * 512 + t] : -1;
  }
  __syncthreads();
  // gather + fp32->bf16 X tile (rows beyond S zero-filled)
  for (int i = tid; i < 68 * 64; i += 256) {
    int row = i >> 6, s4 = i & 63;
    uint2 v = make_uint2(0u, 0u);
    int id = ids_s[row];
    if (id >= 0) {
      const float4 f = *(const float4*)(emb + (size_t)id * 256 + s4 * 4);
      v.x = (unsigned)f2bf(f.x) | ((unsigned)f2bf(f.y) << 16);
      v.y = (unsigned)f2bf(f.z) | ((unsigned)f2bf(f.w) << 16);
    }
    *(uint2*)&Xt[row * 264 + s4 * 4] = v;
  }
  __syncthreads();  // Xt ready; no further barriers

  // per-lane B-fragment bases (bf16 units); frag(e,kc2,nt) = fb[nt] + e*8192 + kc2*4096
  const unsigned short* fb0 = slab + ((size_t)quad * 128 + (wave * 2 + 0) * 16 + m15) * 8;
  const unsigned short* fb1 = fb0 + 128;   // nt=1: +16*8

  bf16x8 fA[4], fB[4];   // [kc2*2+nt]
#pragma unroll
  for (int q = 0; q < 4; ++q) {
    fA[q] = *(const bf16x8*)(((q & 1) ? fb1 : fb0) + (q >> 1) * 4096);
    fB[q] = *(const bf16x8*)(((q & 1) ? fb1 : fb0) + 8192 + (q >> 1) * 4096);
  }

  f32x4 acc[4][2];
#pragma unroll
  for (int mt = 0; mt < 4; ++mt)
#pragma unroll
    for (int nt = 0; nt < 2; ++nt) acc[mt][nt] = (f32x4){0.f, 0.f, 0.f, 0.f};

#define ENTRY(KCQ, FR)                                                          \
  {                                                                             \
    _Pragma("unroll")                                                           \
    for (int kc2 = 0; kc2 < 2; ++kc2) {                                         \
      const int kd0 = ((KCQ) * 2 + kc2) * 32 + quad * 8;                        \
      bf16x8 af[4];                                                             \
      _Pragma("unroll")                                                         \
      for (int mt = 0; mt < 4; ++mt)                                            \
        af[mt] = *(const bf16x8*)&Xt[(shift + mt * 16 + m15) * 264 + kd0];      \
      _Pragma("unroll")                                                         \
      for (int mt = 0; mt < 4; ++mt) {                                          \
        acc[mt][0] = __builtin_amdgcn_mfma_f32_16x16x32_bf16(af[mt], FR[kc2 * 2 + 0], acc[mt][0], 0, 0, 0); \
        acc[mt][1] = __builtin_amdgcn_mfma_f32_16x16x32_bf16(af[mt], FR[kc2 * 2 + 1], acc[mt][1], 0, 0, 0); \
      }                                                                         \
    }                                                                           \
  }

  for (int ep = 0; ep < 28; ++ep) {
    const int e0 = ep * 2;
    const int slice = e0 >> 2;             // e0,e0+1 share slice (e0 even)
    const int shift = (slice < 3) ? slice
                    : (slice < 7) ? (slice - 3)
                    : (slice < 12) ? (slice - 7) : 0;
    const int kcq0 = e0 & 3;

    ENTRY(kcq0, fA);
    if (ep < 27) {
      const int eo = (e0 + 2) * 8192;
#pragma unroll
      for (int q = 0; q < 4; ++q)
        fA[q] = *(const bf16x8*)(((q & 1) ? fb1 : fb0) + eo + (q >> 1) * 4096);
    }
    ENTRY(kcq0 + 1, fB);
    if (ep < 27) {
      const int eo = (e0 + 3) * 8192;
#pragma unroll
      for (int q = 0; q < 4; ++q)
        fB[q] = *(const bf16x8*)(((q & 1) ? fb1 : fb0) + eo + (q >> 1) * 4096);
    }

    // epilogue at group boundaries: ep 5 (conv3), 13 (conv4), 23 (conv5),
    // 25 (node lo), 27 (node hi)
    const int g = (ep == 5) ? 0 : (ep == 13) ? 1 : (ep == 23) ? 2
                : (ep == 25) ? 3 : (ep == 27) ? 4 : -1;
    if (g >= 0) {
      if (g < 3) {
        const int kk = g + 3;
        const float* bb  = (g == 0) ? b3 : (g == 1) ? b4 : b5;
        const float* gg  = (g == 0) ? g3 : (g == 1) ? g4 : g5;
        const float* bbe = (g == 0) ? be3 : (g == 1) ? be4 : be5;
        const int off = 256 + g * 128;     // feats: [node 256][p3 128][p4 128][p5 128]
        const int tmax = 512 - kk;
#pragma unroll
        for (int nt = 0; nt < 2; ++nt) {
          const int n = (wave * 2 + nt) * 16 + m15;
          const float sc = gg[n] * 0.9999950000375f;  // g * 1/sqrt(1+1e-5)
          const float sh = fmaf(sc, bb[n], bbe[n]);
          float mx = 0.f;  // relu floor doubles as init
#pragma unroll
          for (int mt = 0; mt < 4; ++mt)
#pragma unroll
            for (int r = 0; r < 4; ++r) {
              const int t = t0 + mt * 16 + quad * 4 + r;
              const float v = fmaf(sc, acc[mt][nt][r], sh);
              if (t <= tmax) mx = fmaxf(mx, v);
            }
          mx = fmaxf(mx, __shfl_xor(mx, 16));
          mx = fmaxf(mx, __shfl_xor(mx, 32));
          if (quad == 0) atomicMax(&featbuf[b * 640 + off + n], __float_as_uint(mx));
        }
      } else {
        const int base = (g == 3) ? 0 : 128;
#pragma unroll
        for (int nt = 0; nt < 2; ++nt) {
          const int n = (wave * 2 + nt) * 16 + m15;
          const float ct = ctot[base + n];
          float mx = -3.4e38f;
#pragma unroll
          for (int mt = 0; mt < 4; ++mt)
#pragma unroll
            for (int r = 0; r < 4; ++r)
              mx = fmaxf(mx, acc[mt][nt][r] + ct);
          mx = fmaxf(mx, __shfl_xor(mx, 16));
          mx = fmaxf(mx, __shfl_xor(mx, 32));
          if (quad == 0) {
            unsigned bits = __float_as_uint(mx);
            unsigned key = (bits & 0x80000000u) ? ~bits : (bits | 0x80000000u);  // order-preserving
            atomicMax(&featbuf[b * 640 + base + n], key);
          }
        }
      }
      // reset accumulators for the next group
#pragma unroll
      for (int mt = 0; mt < 4; ++mt)
#pragma unroll
        for (int nt = 0; nt < 2; ++nt) acc[mt][nt] = (f32x4){0.f, 0.f, 0.f, 0.f};
    }
  }
#undef ENTRY
}

// ---------------- classifier ----------------
__global__ void k_fin(const unsigned* __restrict__ featbuf, const float* __restrict__ wc,
                      const float* __restrict__ bc, float* __restrict__ out) {
  int b = blockIdx.x, lane = threadIdx.x;  // 64 threads = 1 wave
  float p[10];
#pragma unroll
  for (int c = 0; c < 10; ++c) p[c] = 0.f;
  for (int f = lane; f < 640; f += 64) {
    unsigned u = featbuf[b * 640 + f];
    float v;
    if (f < 256) v = (u & 0x80000000u) ? __uint_as_float(u ^ 0x80000000u) : __uint_as_float(~u);
    else v = __uint_as_float(u);
#pragma unroll
    for (int c = 0; c < 10; ++c) p[c] = fmaf(v, wc[c * 640 + f], p[c]);
  }
#pragma unroll
  for (int c = 0; c < 10; ++c) {
    float s = p[c];
#pragma unroll
    for (int off = 32; off > 0; off >>= 1) s += __shfl_down(s, off);
    if (lane == 0) out[b * 10 + c] = s + bc[c];
  }
}

// ---------------- launcher ----------------
extern "C" void kernel_launch(void* const* d_in, const int* in_sizes, int n_in,
                              void* d_out, int out_size, void* d_ws, size_t ws_size,
                              hipStream_t stream) {
  (void)in_sizes; (void)n_in; (void)out_size; (void)ws_size;
  const int*   ids  = (const int*)d_in[0];
  const float* emb  = (const float*)d_in[1];
  const float* W    = (const float*)d_in[2];
  const float* bode = (const float*)d_in[3];
  const float* w3   = (const float*)d_in[4];
  const float* b3   = (const float*)d_in[5];
  const float* g3   = (const float*)d_in[6];
  const float* be3  = (const float*)d_in[7];
  const float* w4   = (const float*)d_in[8];
  const float* b4   = (const float*)d_in[9];
  const float* g4   = (const float*)d_in[10];
  const float* be4  = (const float*)d_in[11];
  const float* w5   = (const float*)d_in[12];
  const float* b5   = (const float*)d_in[13];
  const float* g5   = (const float*)d_in[14];
  const float* be5  = (const float*)d_in[15];
  const float* wc   = (const float*)d_in[16];
  const float* bc   = (const float*)d_in[17];
  float* out = (float*)d_out;

  float* wsf = (float*)d_ws;
  // ws layout (floats): Bm 0 | c1 65536 | c10 65792 |
  // slab 66048 (14*32768 bf16 = 229376 floats) | featbuf 295424 (40960 uints)
  float* Bm  = wsf;
  float* c1  = wsf + 65536;
  float* c10 = wsf + 65792;
  unsigned short* slab = (unsigned short*)(wsf + 66048);
  unsigned* featbuf = (unsigned*)(wsf + 295424);

  hipLaunchKernelGGL(k_prep1, dim3(640), dim3(256), 0, stream,
                     W, bode, w3, w4, w5, Bm, c1, slab, featbuf);
  hipLaunchKernelGGL(k_prep2, dim3(256), dim3(256), 0, stream, Bm, c1, c10, slab);
  hipLaunchKernelGGL(k_main, dim3(512), dim3(256), 0, stream,
                     ids, emb, slab, c10,
                     b3, g3, be3, b4, g4, be4, b5, g5, be5, featbuf);
  hipLaunchKernelGGL(k_fin, dim3(64), dim3(64), 0, stream, featbuf, wc, bc, out);
}

// Round 11
// 195.732 us; speedup vs baseline: 1.2814x; 1.0222x over previous
//
#include <hip/hip_runtime.h>

// B=64, S=512, D=256, VOCAB=50000, NC=10, N_STEPS=10 (h=0.1), BN eval.
// z_final = z0 @ P10 + c10, P10 = M^10, M = Taylor4(exp(hA)), A = W^T.
// Transpose trick: M = N^T, N = I + B, B = 0.1W + 0.005W^2 + (1e-3/6)W^3 + (1e-4/24)W^4.
// Squared-binomial trick (exact): D = N^2 - I = 2B + B^2;
//   N^10 = (I+D)^5 = sum_k C(5,k) D^k            (k=0..5)
//   ctot = V c1b,  V = sum_{k=0}^{4} C(5,k+1) D^k,  c1b = 2c1 + B c1
// (from T = sum_{j=0}^9 N^j = V (I+N) and commutativity of polynomials in B).
// Row i of every power chains against a FIXED read-only matrix -> 256
// independent blocks, 5 serial passes total after prep1 (was 9).
//
// LESSONS (R1-R10):
//  - Intra-kernel global sync: 70-110us/event (all styles). Multi-dispatch only.
//  - 1024-thread blocks cap VGPR at 64 -> deep load windows spill (R8/R9).
//    256-thread blocks, bv[64] windows stay in registers (R10 confirmed).
//  - Repack gather: consecutive-lane = o gives 3-5KB stride (64 lines/wave).
//    Flip to consecutive-kd (stride k floats, ~10 lines/wave).
//  - k_main: latency-bound at MfmaUtil 25% -> depth-4 B-frag pipeline (R8 body).

typedef short bf16x8 __attribute__((ext_vector_type(8)));
typedef float f32x4 __attribute__((ext_vector_type(4)));

__device__ __forceinline__ unsigned short f2bf(float f) {
  unsigned u = __float_as_uint(f);
  u += 0x7FFFu + ((u >> 16) & 1u);   // RNE; inputs are normal floats
  return (unsigned short)(u >> 16);
}

// acc = sum_k xrow[k] * Y[k][c]; xrow in LDS, Y global row-major, coalesced
// across c. Windows of 64 loads fully in VGPRs (256-thread blocks only!).
__device__ __forceinline__ float dotcol64(const float* __restrict__ xrow,
                                          const float* __restrict__ Y, int c) {
  float a0 = 0.f, a1 = 0.f, a2 = 0.f, a3 = 0.f;
#pragma unroll 1
  for (int w = 0; w < 4; ++w) {
    float bv[64];
#pragma unroll
    for (int v = 0; v < 64; ++v) bv[v] = Y[(w * 64 + v) * 256 + c];
#pragma unroll
    for (int v = 0; v < 64; v += 4) {
      a0 = fmaf(xrow[w * 64 + v + 0], bv[v + 0], a0);
      a1 = fmaf(xrow[w * 64 + v + 1], bv[v + 1], a1);
      a2 = fmaf(xrow[w * 64 + v + 2], bv[v + 2], a2);
      a3 = fmaf(xrow[w * 64 + v + 3], bv[v + 3], a3);
    }
  }
  return (a0 + a1) + (a2 + a3);
}

// ---- d1: blocks 0-255: W-power row chain -> B row + c1[i].
//          blocks 256-639: conv repack (consecutive-kd lanes) + featbuf zero.
__global__ __launch_bounds__(256) void k_prep1(
    const float* __restrict__ W, const float* __restrict__ bode,
    const float* __restrict__ w3c, const float* __restrict__ w4c, const float* __restrict__ w5c,
    float* __restrict__ Bm, float* __restrict__ c1,
    unsigned short* __restrict__ slab, unsigned* __restrict__ featbuf) {
  __shared__ float r1[256], r2[256], r3[256], red[4];
  const int tid = threadIdx.x, blk = blockIdx.x;
  if (blk < 256) {
    const int i = blk;
    r1[tid] = W[i * 256 + tid];
    __syncthreads();
    const float v2 = dotcol64(r1, W, tid);   // W^2[i][tid]
    r2[tid] = v2;
    __syncthreads();
    const float v3 = dotcol64(r2, W, tid);   // W^3[i][tid]
    r3[tid] = v3;
    __syncthreads();
    const float v4 = dotcol64(r3, W, tid);   // W^4[i][tid]
    const float w1 = r1[tid];
    Bm[i * 256 + tid] = 0.1f * w1 + 0.005f * v2
                      + (0.001f / 6.f) * v3 + (0.0001f / 24.f) * v4;
    // c1[i] = 0.1*(b[i] + sum_k b[k]*(0.05 W[i,k] + (0.01/6) W2[i,k] + (0.001/24) W3[i,k]))
    const float q = 0.05f * w1 + (0.01f / 6.f) * v2 + (0.001f / 24.f) * v3;
    float val = bode[tid] * q;
#pragma unroll
    for (int off = 32; off > 0; off >>= 1) val += __shfl_down(val, off);
    if ((tid & 63) == 0) red[tid >> 6] = val;
    __syncthreads();
    if (tid == 0) c1[i] = 0.1f * (bode[i] + ((red[0] + red[1]) + (red[2] + red[3])));
  } else {
    const int base = (blk - 256) * 256 + tid;   // 0..98303
#pragma unroll
    for (int u = 0; u < 4; ++u) {
      int e = base + u * 98304;                 // covers 0..393215 = 12*32768
      int s = e >> 15, r = e & 32767;
      int o = r >> 8, kd = r & 255;             // consecutive lane = consecutive kd
      const float* w; int k, j;
      if (s < 3)      { w = w3c; k = 3; j = s; }
      else if (s < 7) { w = w4c; k = 4; j = s - 3; }
      else            { w = w5c; k = 5; j = s - 7; }
      float val = w[(o * 256 + kd) * k + j];    // w[o][d=kd][j], shape (128,256,k)
      int kc = kd >> 5, quad = (kd >> 3) & 3, q8 = kd & 7;
      slab[s * 32768 + ((kc * 4 + quad) * 128 + o) * 8 + q8] = f2bf(val);
    }
    if (base < 64 * 640) featbuf[base] = 0u;
  }
}

// ---- d2a: block i: D[i] = 2B[i] + B^2[i] (1 pass); c1b[i] = 2c1[i] + dot(B[i],c1).
__global__ __launch_bounds__(256) void k_prep2a(
    const float* __restrict__ Bm, const float* __restrict__ c1v,
    float* __restrict__ Dm, float* __restrict__ c1b) {
  __shared__ float r1[256], c1s[256], red[4];
  const int tid = threadIdx.x, i = blockIdx.x;
  r1[tid] = Bm[i * 256 + tid];
  c1s[tid] = c1v[tid];
  __syncthreads();
  const float v2 = dotcol64(r1, Bm, tid);      // B^2[i][tid]
  Dm[i * 256 + tid] = 2.f * r1[tid] + v2;
  float pd = r1[tid] * c1s[tid];
#pragma unroll
  for (int off = 32; off > 0; off >>= 1) pd += __shfl_down(pd, off);
  if ((tid & 63) == 0) red[tid >> 6] = pd;
  __syncthreads();
  if (tid == 0) c1b[i] = 2.f * c1s[i] + ((red[0] + red[1]) + (red[2] + red[3]));
}

// ---- d2b: block i: chain D[i] -> D^5[i] (4 passes, Y=D read-only).
// n10 = I + 5D + 10D^2 + 10D^3 + 5D^4 + D^5 ; scatter row to slab node slices.
// ct  = 5 c1b[i] + 10 dot(D,c1b) + 10 dot(D^2,c1b) + 5 dot(D^3,c1b) + dot(D^4,c1b).
__global__ __launch_bounds__(256) void k_prep2b(
    const float* __restrict__ Dm, const float* __restrict__ c1bv,
    float* __restrict__ c10, unsigned short* __restrict__ slab) {
  __shared__ float curs[256], cbs[256], red[4];
  const int tid = threadIdx.x, i = blockIdx.x;
  const float coefN[6] = {1.f, 5.f, 10.f, 10.f, 5.f, 1.f};   // C(5,k)
  const float coefC[5] = {5.f, 10.f, 10.f, 5.f, 1.f};        // C(5,k+1)
  float v = Dm[i * 256 + tid];
  curs[tid] = v;
  cbs[tid] = c1bv[tid];
  __syncthreads();
  float n10 = ((i == tid) ? 1.f : 0.f) + coefN[1] * v;
  float pd = v * cbs[tid];
#pragma unroll
  for (int off = 32; off > 0; off >>= 1) pd += __shfl_down(pd, off);
  if ((tid & 63) == 0) red[tid >> 6] = pd;
  __syncthreads();
  float ct = coefC[0] * cbs[i] + coefC[1] * ((red[0] + red[1]) + (red[2] + red[3]));

#pragma unroll 1
  for (int k = 2; k <= 5; ++k) {
    v = dotcol64(curs, Dm, tid);        // D^k[i][tid]
    __syncthreads();                    // all reads of curs done
    curs[tid] = v;
    n10 = fmaf(coefN[k], v, n10);
    float pdk = v * cbs[tid];
#pragma unroll
    for (int off = 32; off > 0; off >>= 1) pdk += __shfl_down(pdk, off);
    if ((tid & 63) == 0) red[tid >> 6] = pdk;
    __syncthreads();                    // red ready; curs visible
    if (k <= 4) ct = fmaf(coefC[k], (red[0] + red[1]) + (red[2] + red[3]), ct);
  }

  // scatter n10: element (kd=tid, o=i) of the node B-matrix (P10[kd][o]=N10[o][kd])
  {
    const int o = i, kd = tid;
    const int kc = kd >> 5, quad = (kd >> 3) & 3, q8 = kd & 7;
    slab[(12 + (o >> 7)) * 32768 + ((kc * 4 + quad) * 128 + (o & 127)) * 8 + q8] = f2bf(n10);
  }
  if (tid == 0) c10[i] = ct;
}

// ---------------- fused main kernel (depth-4 B-frag pipeline, R8 body) ----------------
// grid 512 = 64 batches x 8 t-chunks of 64. 256 threads = 4 waves.
// LDS: only the X tile. B-fragments read per-wave directly from the
// L2-resident slab with a 4-deep register pipeline; no barriers in main loop.

__global__ __launch_bounds__(256, 2) void k_main(
    const int* __restrict__ ids, const float* __restrict__ emb,
    const unsigned short* __restrict__ slab, const float* __restrict__ ctot,
    const float* __restrict__ b3, const float* __restrict__ g3, const float* __restrict__ be3,
    const float* __restrict__ b4, const float* __restrict__ g4, const float* __restrict__ be4,
    const float* __restrict__ b5, const float* __restrict__ g5, const float* __restrict__ be5,
    unsigned* __restrict__ featbuf) {
  __shared__ alignas(16) unsigned short Xt[68 * 264];
  __shared__ int ids_s[68];
  const int tid = threadIdx.x;
  const int blk = blockIdx.x;
  const int b = blk >> 3;
  const int t0 = (blk & 7) * 64;
  const int lane = tid & 63;
  const int wave = tid >> 6;
  const int m15 = lane & 15;
  const int quad = lane >> 4;

  if (tid < 68) {
    int t = t0 + tid;
    ids_s[tid] = (t < 512) ? ids[b * 512 + t] : -1;
  }
  __syncthreads();

  // per-lane B-fragment base; frag(e,kc2,nt) = fb0 + e*8192 + kc2*4096 + nt*128
  const unsigned short* fb0 = slab + ((size_t)quad * 128 + wave * 2 * 16 + m15) * 8;
  bf16x8 fA[4], fB[4], fC[4], fD[4];   // [kc2*2+nt], 4-deep entry pipeline
#define LDFRAG(DST, EN)                                                         \
  {                                                                             \
    const unsigned short* p_ = fb0 + (EN) * 8192;                               \
    DST[0] = *(const bf16x8*)(p_);                                              \
    DST[1] = *(const bf16x8*)(p_ + 128);                                        \
    DST[2] = *(const bf16x8*)(p_ + 4096);                                       \
    DST[3] = *(const bf16x8*)(p_ + 4096 + 128);                                 \
  }
  LDFRAG(fA, 0) LDFRAG(fB, 1) LDFRAG(fC, 2) LDFRAG(fD, 3)

  // gather + fp32->bf16 X tile (overlaps the frag loads above)
  for (int i = tid; i < 68 * 64; i += 256) {
    int row = i >> 6, s4 = i & 63;
    uint2 v = make_uint2(0u, 0u);
    int id = ids_s[row];
    if (id >= 0) {
      const float4 f = *(const float4*)(emb + (size_t)id * 256 + s4 * 4);
      v.x = (unsigned)f2bf(f.x) | ((unsigned)f2bf(f.y) << 16);
      v.y = (unsigned)f2bf(f.z) | ((unsigned)f2bf(f.w) << 16);
    }
    *(uint2*)&Xt[row * 264 + s4 * 4] = v;
  }
  __syncthreads();  // Xt ready; no further barriers

  f32x4 acc[4][2];
#pragma unroll
  for (int mt = 0; mt < 4; ++mt)
#pragma unroll
    for (int nt = 0; nt < 2; ++nt) acc[mt][nt] = (f32x4){0.f, 0.f, 0.f, 0.f};

#define ENTRY(KCQ, FR)                                                          \
  {                                                                             \
    _Pragma("unroll")                                                           \
    for (int kc2 = 0; kc2 < 2; ++kc2) {                                         \
      const int kd0 = ((KCQ) * 2 + kc2) * 32 + quad * 8;                        \
      bf16x8 af[4];                                                             \
      _Pragma("unroll")                                                         \
      for (int mt = 0; mt < 4; ++mt)                                            \
        af[mt] = *(const bf16x8*)&Xt[(shift + mt * 16 + m15) * 264 + kd0];      \
      _Pragma("unroll")                                                         \
      for (int mt = 0; mt < 4; ++mt) {                                          \
        acc[mt][0] = __builtin_amdgcn_mfma_f32_16x16x32_bf16(af[mt], FR[kc2 * 2 + 0], acc[mt][0], 0, 0, 0); \
        acc[mt][1] = __builtin_amdgcn_mfma_f32_16x16x32_bf16(af[mt], FR[kc2 * 2 + 1], acc[mt][1], 0, 0, 0); \
      }                                                                         \
    }                                                                           \
  }

  // entries e = eq*4 + j; slice = eq; kcq = j; epilogues at eq 2,6,11,12,13.
  for (int eq = 0; eq < 14; ++eq) {
    const int shift = (eq < 3) ? eq : (eq < 7) ? (eq - 3) : (eq < 12) ? (eq - 7) : 0;

    ENTRY(0, fA) if (eq < 13) LDFRAG(fA, (eq + 1) * 4 + 0)
    ENTRY(1, fB) if (eq < 13) LDFRAG(fB, (eq + 1) * 4 + 1)
    ENTRY(2, fC) if (eq < 13) LDFRAG(fC, (eq + 1) * 4 + 2)
    ENTRY(3, fD) if (eq < 13) LDFRAG(fD, (eq + 1) * 4 + 3)

    const int g = (eq == 2) ? 0 : (eq == 6) ? 1 : (eq == 11) ? 2
                : (eq == 12) ? 3 : (eq == 13) ? 4 : -1;
    if (g >= 0) {
      if (g < 3) {
        const int kk = g + 3;
        const float* bb  = (g == 0) ? b3 : (g == 1) ? b4 : b5;
        const float* gg  = (g == 0) ? g3 : (g == 1) ? g4 : g5;
        const float* bbe = (g == 0) ? be3 : (g == 1) ? be4 : be5;
        const int off = 256 + g * 128;     // feats: [node 256][p3 128][p4 128][p5 128]
        const int tmax = 512 - kk;
#pragma unroll
        for (int nt = 0; nt < 2; ++nt) {
          const int n = (wave * 2 + nt) * 16 + m15;
          const float sc = gg[n] * 0.9999950000375f;  // g * 1/sqrt(1+1e-5)
          const float sh = fmaf(sc, bb[n], bbe[n]);
          float mx = 0.f;  // relu floor doubles as init
#pragma unroll
          for (int mt = 0; mt < 4; ++mt)
#pragma unroll
            for (int r = 0; r < 4; ++r) {
              const int t = t0 + mt * 16 + quad * 4 + r;
              const float v = fmaf(sc, acc[mt][nt][r], sh);
              if (t <= tmax) mx = fmaxf(mx, v);
            }
          mx = fmaxf(mx, __shfl_xor(mx, 16));
          mx = fmaxf(mx, __shfl_xor(mx, 32));
          if (quad == 0) atomicMax(&featbuf[b * 640 + off + n], __float_as_uint(mx));
        }
      } else {
        const int base = (g == 3) ? 0 : 128;
#pragma unroll
        for (int nt = 0; nt < 2; ++nt) {
          const int n = (wave * 2 + nt) * 16 + m15;
          const float ct = ctot[base + n];
          float mx = -3.4e38f;
#pragma unroll
          for (int mt = 0; mt < 4; ++mt)
#pragma unroll
            for (int r = 0; r < 4; ++r)
              mx = fmaxf(mx, acc[mt][nt][r] + ct);
          mx = fmaxf(mx, __shfl_xor(mx, 16));
          mx = fmaxf(mx, __shfl_xor(mx, 32));
          if (quad == 0) {
            unsigned bits = __float_as_uint(mx);
            unsigned key = (bits & 0x80000000u) ? ~bits : (bits | 0x80000000u);  // order-preserving
            atomicMax(&featbuf[b * 640 + base + n], key);
          }
        }
      }
#pragma unroll
      for (int mt = 0; mt < 4; ++mt)
#pragma unroll
        for (int nt = 0; nt < 2; ++nt) acc[mt][nt] = (f32x4){0.f, 0.f, 0.f, 0.f};
    }
  }
#undef ENTRY
#undef LDFRAG
}

// ---------------- classifier ----------------
__global__ void k_fin(const unsigned* __restrict__ featbuf, const float* __restrict__ wc,
                      const float* __restrict__ bc, float* __restrict__ out) {
  int b = blockIdx.x, lane = threadIdx.x;  // 64 threads = 1 wave
  float p[10];
#pragma unroll
  for (int c = 0; c < 10; ++c) p[c] = 0.f;
  for (int f = lane; f < 640; f += 64) {
    unsigned u = featbuf[b * 640 + f];
    float v;
    if (f < 256) v = (u & 0x80000000u) ? __uint_as_float(u ^ 0x80000000u) : __uint_as_float(~u);
    else v = __uint_as_float(u);
#pragma unroll
    for (int c = 0; c < 10; ++c) p[c] = fmaf(v, wc[c * 640 + f], p[c]);
  }
#pragma unroll
  for (int c = 0; c < 10; ++c) {
    float s = p[c];
#pragma unroll
    for (int off = 32; off > 0; off >>= 1) s += __shfl_down(s, off);
    if (lane == 0) out[b * 10 + c] = s + bc[c];
  }
}

// ---------------- launcher ----------------
extern "C" void kernel_launch(void* const* d_in, const int* in_sizes, int n_in,
                              void* d_out, int out_size, void* d_ws, size_t ws_size,
                              hipStream_t stream) {
  (void)in_sizes; (void)n_in; (void)out_size; (void)ws_size;
  const int*   ids  = (const int*)d_in[0];
  const float* emb  = (const float*)d_in[1];
  const float* W    = (const float*)d_in[2];
  const float* bode = (const float*)d_in[3];
  const float* w3   = (const float*)d_in[4];
  const float* b3   = (const float*)d_in[5];
  const float* g3   = (const float*)d_in[6];
  const float* be3  = (const float*)d_in[7];
  const float* w4   = (const float*)d_in[8];
  const float* b4   = (const float*)d_in[9];
  const float* g4   = (const float*)d_in[10];
  const float* be4  = (const float*)d_in[11];
  const float* w5   = (const float*)d_in[12];
  const float* b5   = (const float*)d_in[13];
  const float* g5   = (const float*)d_in[14];
  const float* be5  = (const float*)d_in[15];
  const float* wc   = (const float*)d_in[16];
  const float* bc   = (const float*)d_in[17];
  float* out = (float*)d_out;

  float* wsf = (float*)d_ws;
  // ws layout (floats): Bm 0 | Dm 65536 | c1 131072 | c1b 131328 | c10 131584 |
  // slab 131840 (14*32768 bf16 = 229376 floats) | featbuf 361216 (40960 uints)
  float* Bm  = wsf;
  float* Dm  = wsf + 65536;
  float* c1  = wsf + 131072;
  float* c1b = wsf + 131328;
  float* c10 = wsf + 131584;
  unsigned short* slab = (unsigned short*)(wsf + 131840);
  unsigned* featbuf = (unsigned*)(wsf + 361216);

  hipLaunchKernelGGL(k_prep1, dim3(640), dim3(256), 0, stream,
                     W, bode, w3, w4, w5, Bm, c1, slab, featbuf);
  hipLaunchKernelGGL(k_prep2a, dim3(256), dim3(256), 0, stream, Bm, c1, Dm, c1b);
  hipLaunchKernelGGL(k_prep2b, dim3(256), dim3(256), 0, stream, Dm, c1b, c10, slab);
  hipLaunchKernelGGL(k_main, dim3(512), dim3(256), 0, stream,
                     ids, emb, slab, c10,
                     b3, g3, be3, b4, g4, be4, b5, g5, be5, featbuf);
  hipLaunchKernelGGL(k_fin, dim3(64), dim3(64), 0, stream, featbuf, wc, bc, out);
}